// Round 4
// baseline (254.298 us; speedup 1.0000x reference)
//
#include <hip/hip_runtime.h>
#include <math.h>

#define NN 50000
#define NE 800000
#define DD 128
#define NBKT 256            // buckets; bucket = row / RPB (one block per CU)
#define RPB 196             // rows per bucket (256*196 = 50176 >= NN)
#define BCAP 3840           // per-bucket capacity (mean 3136, sigma 56 -> ~12.5 sigma)
#define CHUNK 2048          // edges per bin_kernel block
#define NCHUNK ((NE + CHUNK - 1) / CHUNK)   // 391
#define SPMM_NBLK (NN / 16) // 3125

// ---------------- bf16 helpers (x stored as bf16 pairs packed in uint) ----------------
static __device__ __forceinline__ float blo(unsigned int p) { return __uint_as_float(p << 16); }
static __device__ __forceinline__ float bhi(unsigned int p) { return __uint_as_float(p & 0xffff0000u); }
static __device__ __forceinline__ unsigned int pack2bf(float a, float b) {
    unsigned int ua = __float_as_uint(a);
    unsigned int ub = __float_as_uint(b);
    ua = ua + 0x7FFFu + ((ua >> 16) & 1u);
    ub = ub + 0x7FFFu + ((ub >> 16) & 1u);
    return (ua >> 16) | (ub & 0xffff0000u);
}

// ---------------- pass 1: LDS counting-sort edges into 256 coarse buckets ----------------
// payload: uint2{ row | col<<16, val_bits }  (row, col < 65536)
static __global__ __launch_bounds__(512) void bin_kernel(
    const int* __restrict__ erow, const int* __restrict__ ecol, const float* __restrict__ eval_,
    int* __restrict__ bucket_cursor, uint2* __restrict__ binned) {
    __shared__ uint2 sorted[CHUNK];
    __shared__ unsigned char sbin[CHUNK];
    __shared__ int hist[NBKT];
    __shared__ int bstart[NBKT];
    __shared__ int bcur[NBKT];
    __shared__ int gbase[NBKT];
    __shared__ int tmp[NBKT];

    int t = threadIdx.x;
    int cbase = blockIdx.x * CHUNK;
    int cn = NE - cbase; if (cn > CHUNK) cn = CHUNK;

    for (int i = t; i < NBKT; i += 512) hist[i] = 0;
    __syncthreads();

    unsigned int rc[4]; unsigned int vv[4]; int bb[4];
    int nloc = 0;
    for (int i = t; i < cn; i += 512) {
        int g = cbase + i;
        int r = erow[g];
        int c = ecol[g];
        float v = eval_[g];
        rc[nloc] = (unsigned)r | ((unsigned)c << 16);
        vv[nloc] = __float_as_uint(v);
        int b = r / RPB;            // compiler emits magic-multiply
        bb[nloc] = b;
        atomicAdd(&hist[b], 1);
        ++nloc;
    }
    __syncthreads();

    // exclusive scan of hist over 256 entries (first 256 threads; all hit barriers)
    int hv = (t < NBKT) ? hist[t] : 0;
    if (t < NBKT) tmp[t] = hv;
    __syncthreads();
    for (int off = 1; off < NBKT; off <<= 1) {
        int u = (t < NBKT && t >= off) ? tmp[t - off] : 0;
        __syncthreads();
        if (t < NBKT) tmp[t] += u;
        __syncthreads();
    }
    if (t < NBKT) {
        int ex = tmp[t] - hv;
        bstart[t] = ex;
        bcur[t] = ex;
        gbase[t] = atomicAdd(&bucket_cursor[t], hv);  // reserve contiguous run in bucket region
    }
    __syncthreads();

    // scatter into LDS (sorted by bucket)
    for (int k = 0; k < nloc; ++k) {
        int pos = atomicAdd(&bcur[bb[k]], 1);
        sorted[pos] = make_uint2(rc[k], vv[k]);
        sbin[pos] = (unsigned char)bb[k];
    }
    __syncthreads();

    // coalesced write-out: consecutive i in same bucket -> consecutive global slots
    for (int i = t; i < cn; i += 512) {
        int b = sbin[i];
        binned[(size_t)b * BCAP + gbase[b] + (i - bstart[b])] = sorted[i];
    }
}

// ---------------- pass 2: per-bucket sort by row -> CSR + row_start + deg ----------
static __global__ __launch_bounds__(512) void sort_kernel(
    const uint2* __restrict__ binned, const int* __restrict__ bucket_cursor,
    uint2* __restrict__ csr, int* __restrict__ row_start, float* __restrict__ deg) {
    __shared__ uint2 buf[BCAP];       // 30 KB
    __shared__ int hist[RPB];
    __shared__ int rcur[RPB];
    __shared__ float fdeg[RPB];
    __shared__ int pscan[NBKT];
    int b = blockIdx.x;
    int t = threadIdx.x;
    int lo = b * RPB;

    // inclusive scan over all bucket counts -> per-block base + count
    int pv = (t < NBKT) ? bucket_cursor[t] : 0;
    if (t < NBKT) pscan[t] = pv;
    if (t < RPB) { hist[t] = 0; fdeg[t] = 0.0f; }
    __syncthreads();
    for (int off = 1; off < NBKT; off <<= 1) {
        int u = (t < NBKT && t >= off) ? pscan[t - off] : 0;
        __syncthreads();
        if (t < NBKT) pscan[t] += u;
        __syncthreads();
    }
    int gb = (b == 0) ? 0 : pscan[b - 1];
    int cnt = pscan[b] - gb;

    for (int i = t; i < cnt; i += 512) {
        uint2 e = binned[(size_t)b * BCAP + i];
        buf[i] = e;
        int rr = (int)(e.x & 0xFFFFu) - lo;
        atomicAdd(&hist[rr], 1);
        atomicAdd(&fdeg[rr], __uint_as_float(e.y));
    }
    __syncthreads();
    // inclusive scan of per-row counts (196 entries)
    int hv = (t < RPB) ? hist[t] : 0;
    if (t < RPB) rcur[t] = hv;
    __syncthreads();
    for (int off = 1; off < RPB; off <<= 1) {
        int u = (t < RPB && t >= off) ? rcur[t - off] : 0;
        __syncthreads();
        if (t < RPB) rcur[t] += u;
        __syncthreads();
    }
    if (t < RPB) {
        int excl = rcur[t] - hv;
        int r = lo + t;
        if (r < NN) {
            row_start[r] = gb + excl;
            float d = fdeg[t];
            deg[r] = (d == 0.0f) ? 1.0f : d;
        }
        rcur[t] = excl;
    }
    if (b == NBKT - 1 && t == 0) row_start[NN] = gb + cnt;
    __syncthreads();
    for (int i = t; i < cnt; i += 512) {
        uint2 e = buf[i];
        int rr = (int)(e.x & 0xFFFFu) - lo;
        int pos = atomicAdd(&rcur[rr], 1);
        csr[(size_t)gb + pos] = make_uint2(e.x >> 16, e.y);
    }
}

// ---------------- x0 init + ternary pattern pack ----------------
// Writes dense bf16 x0 (fallback path) AND the packed form pks[node]:
//   words 0..7 : 2-bit code per col (0=zero, 1=+scale, 3=-scale), col d at bits 2d
//   word 8     : f32 scale = rowmax|R| * deg^-1/2
// Verifies "all nonzeros in a row share one magnitude"; on violation sets *flag
// so hop 1 uses the dense path (correct for arbitrary R).
static __global__ __launch_bounds__(256) void pk_kernel(
    const float* __restrict__ R, const float* __restrict__ deg,
    uint4* __restrict__ x0, unsigned int* __restrict__ pks, int* __restrict__ flag) {
    int idx = blockIdx.x * 256 + threadIdx.x;   // over NN*16 (exact grid)
    int node = idx >> 4;
    int sub = idx & 15;
    float sc = rsqrtf(deg[node]);               // deg already has 0 -> 1 fix
    const float4* __restrict__ R4 = (const float4*)R;
    float4 f0 = R4[(size_t)idx * 2];
    float4 f1 = R4[(size_t)idx * 2 + 1];
    x0[idx] = make_uint4(pack2bf(f0.x * sc, f0.y * sc), pack2bf(f0.z * sc, f0.w * sc),
                         pack2bf(f1.x * sc, f1.y * sc), pack2bf(f1.z * sc, f1.w * sc));

    float v[8] = {f0.x, f0.y, f0.z, f0.w, f1.x, f1.y, f1.z, f1.w};
    float am = 0.0f;
#pragma unroll
    for (int j = 0; j < 8; ++j) am = fmaxf(am, fabsf(v[j]));
#pragma unroll
    for (int m = 1; m < 16; m <<= 1) am = fmaxf(am, __shfl_xor(am, m));  // row max |R|

    bool viol = false;
    unsigned int code16 = 0;
#pragma unroll
    for (int j = 0; j < 8; ++j) {
        float x = v[j];
        unsigned int code = (x == 0.0f) ? 0u : ((x < 0.0f) ? 3u : 1u);
        if (x != 0.0f && fabsf(x) != am) viol = true;   // bit-exact uniform-magnitude check
        code16 |= code << (2 * j);
    }
    unsigned int other = __shfl_xor(code16, 1);
    unsigned int word = (sub & 1) ? ((code16 << 16) | other) : (code16 | (other << 16));
    if (!(sub & 1)) pks[(size_t)node * 16 + (sub >> 1)] = word;
    if (sub == 0) pks[(size_t)node * 16 + 8] = __float_as_uint(am * sc);
    if (viol) atomicOr(flag, 1);
}

// ---------------- hop 1: SpMM from ternary-packed x0 (64B/edge instead of 256B) ------
static __global__ __launch_bounds__(256) void spmm_first_kernel(
    const int* __restrict__ row_start, const uint2* __restrict__ csr,
    const unsigned int* __restrict__ pks, const uint4* __restrict__ x4,
    const float* __restrict__ deg, const int* __restrict__ flag,
    uint4* __restrict__ x_next4, float* __restrict__ s_out, float weight) {
    int wave = threadIdx.x >> 6;
    int lane = threadIdx.x & 63;
    int quarter = lane >> 4;  // 0..3 : which row of the wave's 4
    int sub = lane & 15;      // col group: cols [8*sub, 8*sub+7]
    int row = blockIdx.x * 16 + wave * 4 + quarter;
    int s = row_start[row];
    int e = row_start[row + 1];

    float a[8] = {0.f, 0.f, 0.f, 0.f, 0.f, 0.f, 0.f, 0.f};

    if (*flag == 0) {
        // ternary path: per edge, lane sub loads pattern word (sub>>1) + broadcast scale
        size_t wofs = (size_t)(sub >> 1);
        int hsh = (sub & 1) * 16;
        for (int base = s; base < e; base += 16) {
            int j = base + sub;
            int cl = 0;
            float vl = 0.0f;
            if (j < e) { uint2 t2 = csr[j]; cl = (int)t2.x; vl = __uint_as_float(t2.y); }
            int cnt = e - base; if (cnt > 16) cnt = 16;
            for (int k = 0; k < cnt; k += 4) {
                int l0 = quarter * 16 + k;
                int c0 = __shfl(cl, l0);
                int c1 = __shfl(cl, l0 + 1);
                int c2 = __shfl(cl, l0 + 2);
                int c3 = __shfl(cl, l0 + 3);
                float v0 = __shfl(vl, l0);
                float v1 = __shfl(vl, l0 + 1);
                float v2 = __shfl(vl, l0 + 2);
                float v3 = __shfl(vl, l0 + 3);  // padded slots: v=0 -> u=0 -> contribute 0
                unsigned int w0 = pks[(size_t)c0 * 16 + wofs];
                unsigned int w1 = pks[(size_t)c1 * 16 + wofs];
                unsigned int w2 = pks[(size_t)c2 * 16 + wofs];
                unsigned int w3 = pks[(size_t)c3 * 16 + wofs];
                float u0 = v0 * __uint_as_float(pks[(size_t)c0 * 16 + 8]);
                float u1 = v1 * __uint_as_float(pks[(size_t)c1 * 16 + 8]);
                float u2 = v2 * __uint_as_float(pks[(size_t)c2 * 16 + 8]);
                float u3 = v3 * __uint_as_float(pks[(size_t)c3 * 16 + 8]);
                unsigned int h0 = (w0 >> hsh) & 0xFFFFu;
                unsigned int h1 = (w1 >> hsh) & 0xFFFFu;
                unsigned int h2 = (w2 >> hsh) & 0xFFFFu;
                unsigned int h3 = (w3 >> hsh) & 0xFFFFu;
#pragma unroll
                for (int jj = 0; jj < 8; ++jj) {
                    int d0 = (int)((h0 >> (2 * jj)) & 3u);
                    int d1 = (int)((h1 >> (2 * jj)) & 3u);
                    int d2 = (int)((h2 >> (2 * jj)) & 3u);
                    int d3 = (int)((h3 >> (2 * jj)) & 3u);
                    a[jj] += u0 * (float)((d0 & 1) - (d0 & 2));
                    a[jj] += u1 * (float)((d1 & 1) - (d1 & 2));
                    a[jj] += u2 * (float)((d2 & 1) - (d2 & 2));
                    a[jj] += u3 * (float)((d3 & 1) - (d3 & 2));
                }
            }
        }
    } else {
        // fallback: dense bf16 gather (arbitrary R)
        for (int base = s; base < e; base += 16) {
            int j = base + sub;
            int cl = 0;
            float vl = 0.0f;
            if (j < e) { uint2 t2 = csr[j]; cl = (int)t2.x; vl = __uint_as_float(t2.y); }
            int cnt = e - base; if (cnt > 16) cnt = 16;
            for (int k = 0; k < cnt; k += 4) {
                int l0 = quarter * 16 + k;
                int c0 = __shfl(cl, l0);
                int c1 = __shfl(cl, l0 + 1);
                int c2 = __shfl(cl, l0 + 2);
                int c3 = __shfl(cl, l0 + 3);
                float v0 = __shfl(vl, l0);
                float v1 = __shfl(vl, l0 + 1);
                float v2 = __shfl(vl, l0 + 2);
                float v3 = __shfl(vl, l0 + 3);
                uint4 p0 = x4[(size_t)c0 * 16 + sub];
                uint4 p1 = x4[(size_t)c1 * 16 + sub];
                uint4 p2 = x4[(size_t)c2 * 16 + sub];
                uint4 p3 = x4[(size_t)c3 * 16 + sub];
                a[0] += v0 * blo(p0.x); a[1] += v0 * bhi(p0.x); a[2] += v0 * blo(p0.y); a[3] += v0 * bhi(p0.y);
                a[4] += v0 * blo(p0.z); a[5] += v0 * bhi(p0.z); a[6] += v0 * blo(p0.w); a[7] += v0 * bhi(p0.w);
                a[0] += v1 * blo(p1.x); a[1] += v1 * bhi(p1.x); a[2] += v1 * blo(p1.y); a[3] += v1 * bhi(p1.y);
                a[4] += v1 * blo(p1.z); a[5] += v1 * bhi(p1.z); a[6] += v1 * blo(p1.w); a[7] += v1 * bhi(p1.w);
                a[0] += v2 * blo(p2.x); a[1] += v2 * bhi(p2.x); a[2] += v2 * blo(p2.y); a[3] += v2 * bhi(p2.y);
                a[4] += v2 * blo(p2.z); a[5] += v2 * bhi(p2.z); a[6] += v2 * blo(p2.w); a[7] += v2 * bhi(p2.w);
                a[0] += v3 * blo(p3.x); a[1] += v3 * bhi(p3.x); a[2] += v3 * blo(p3.y); a[3] += v3 * bhi(p3.y);
                a[4] += v3 * blo(p3.z); a[5] += v3 * bhi(p3.z); a[6] += v3 * blo(p3.w); a[7] += v3 * bhi(p3.w);
            }
        }
    }

    float id = 1.0f / deg[row];
#pragma unroll
    for (int jj = 0; jj < 8; ++jj) a[jj] *= id;

    float ss = a[0]*a[0] + a[1]*a[1] + a[2]*a[2] + a[3]*a[3]
             + a[4]*a[4] + a[5]*a[5] + a[6]*a[6] + a[7]*a[7];
#pragma unroll
    for (int m = 1; m <= 8; m <<= 1) ss += __shfl_xor(ss, m);
    float nrm = fmaxf(sqrtf(ss), 1e-12f);

    x_next4[(size_t)row * 16 + sub] = make_uint4(pack2bf(a[0], a[1]), pack2bf(a[2], a[3]),
                                                 pack2bf(a[4], a[5]), pack2bf(a[6], a[7]));
    if (sub == 0) s_out[row] = weight / nrm;
}

// ---------------- fused SpMM + inv_deg + row-norm scalar (hops 2-3) ----------------
// 256 threads = 4 waves; each wave handles 4 rows, one per 16-lane quarter.
static __global__ __launch_bounds__(256) void spmm_fused_kernel(
    const int* __restrict__ row_start, const uint2* __restrict__ csr,
    const uint4* __restrict__ x4, const float* __restrict__ deg,
    uint4* __restrict__ x_next4, float* __restrict__ s_out, float weight) {
    int wave = threadIdx.x >> 6;
    int lane = threadIdx.x & 63;
    int quarter = lane >> 4;  // 0..3 : which row of the wave's 4
    int sub = lane & 15;      // col group: cols [8*sub, 8*sub+7]
    int row = blockIdx.x * 16 + wave * 4 + quarter;
    int s = row_start[row];
    int e = row_start[row + 1];

    float a0 = 0.f, a1 = 0.f, a2 = 0.f, a3 = 0.f, a4 = 0.f, a5 = 0.f, a6 = 0.f, a7 = 0.f;
    for (int base = s; base < e; base += 16) {
        int j = base + sub;
        int cl = 0;
        float vl = 0.0f;
        if (j < e) { uint2 t2 = csr[j]; cl = (int)t2.x; vl = __uint_as_float(t2.y); }
        int cnt = e - base; if (cnt > 16) cnt = 16;
        for (int k = 0; k < cnt; k += 4) {
            int l0 = quarter * 16 + k;
            int c0 = __shfl(cl, l0);
            int c1 = __shfl(cl, l0 + 1);
            int c2 = __shfl(cl, l0 + 2);
            int c3 = __shfl(cl, l0 + 3);
            float v0 = __shfl(vl, l0);
            float v1 = __shfl(vl, l0 + 1);
            float v2 = __shfl(vl, l0 + 2);
            float v3 = __shfl(vl, l0 + 3);  // entries past cnt have vl=0 -> contribute 0
            uint4 p0 = x4[(size_t)c0 * 16 + sub];
            uint4 p1 = x4[(size_t)c1 * 16 + sub];
            uint4 p2 = x4[(size_t)c2 * 16 + sub];
            uint4 p3 = x4[(size_t)c3 * 16 + sub];
            a0 += v0 * blo(p0.x); a1 += v0 * bhi(p0.x); a2 += v0 * blo(p0.y); a3 += v0 * bhi(p0.y);
            a4 += v0 * blo(p0.z); a5 += v0 * bhi(p0.z); a6 += v0 * blo(p0.w); a7 += v0 * bhi(p0.w);
            a0 += v1 * blo(p1.x); a1 += v1 * bhi(p1.x); a2 += v1 * blo(p1.y); a3 += v1 * bhi(p1.y);
            a4 += v1 * blo(p1.z); a5 += v1 * bhi(p1.z); a6 += v1 * blo(p1.w); a7 += v1 * bhi(p1.w);
            a0 += v2 * blo(p2.x); a1 += v2 * bhi(p2.x); a2 += v2 * blo(p2.y); a3 += v2 * bhi(p2.y);
            a4 += v2 * blo(p2.z); a5 += v2 * bhi(p2.z); a6 += v2 * blo(p2.w); a7 += v2 * bhi(p2.w);
            a0 += v3 * blo(p3.x); a1 += v3 * bhi(p3.x); a2 += v3 * blo(p3.y); a3 += v3 * bhi(p3.y);
            a4 += v3 * blo(p3.z); a5 += v3 * bhi(p3.z); a6 += v3 * blo(p3.w); a7 += v3 * bhi(p3.w);
        }
    }

    float id = 1.0f / deg[row];
    a0 *= id; a1 *= id; a2 *= id; a3 *= id; a4 *= id; a5 *= id; a6 *= id; a7 *= id;

    float ss = a0 * a0 + a1 * a1 + a2 * a2 + a3 * a3 + a4 * a4 + a5 * a5 + a6 * a6 + a7 * a7;
#pragma unroll
    for (int m = 1; m <= 8; m <<= 1) ss += __shfl_xor(ss, m);
    float nrm = fmaxf(sqrtf(ss), 1e-12f);

    x_next4[(size_t)row * 16 + sub] = make_uint4(pack2bf(a0, a1), pack2bf(a2, a3),
                                                 pack2bf(a4, a5), pack2bf(a6, a7));
    if (sub == 0) s_out[row] = weight / nrm;
}

// ---------------- hop 4: SpMM + combine acc(out) + per-block column stats ----------------
static __global__ __launch_bounds__(256) void spmm_last_kernel(
    const int* __restrict__ row_start, const uint2* __restrict__ csr,
    const uint4* __restrict__ xin, const float* __restrict__ deg,
    const uint4* __restrict__ x1, const uint4* __restrict__ x2, const uint4* __restrict__ x3,
    const float* __restrict__ s1, const float* __restrict__ s2, const float* __restrict__ s3,
    float* __restrict__ out, float* __restrict__ psum, float* __restrict__ psumsq, float weight) {
    __shared__ float shs[256 * 8];
    __shared__ float shq[256 * 8];
    int wave = threadIdx.x >> 6;
    int lane = threadIdx.x & 63;
    int quarter = lane >> 4;
    int sub = lane & 15;
    int row = blockIdx.x * 16 + wave * 4 + quarter;
    int s = row_start[row];
    int e = row_start[row + 1];

    float a0 = 0.f, a1 = 0.f, a2 = 0.f, a3 = 0.f, a4 = 0.f, a5 = 0.f, a6 = 0.f, a7 = 0.f;
    for (int base = s; base < e; base += 16) {
        int j = base + sub;
        int cl = 0;
        float vl = 0.0f;
        if (j < e) { uint2 t2 = csr[j]; cl = (int)t2.x; vl = __uint_as_float(t2.y); }
        int cnt = e - base; if (cnt > 16) cnt = 16;
        for (int k = 0; k < cnt; k += 4) {
            int l0 = quarter * 16 + k;
            int c0 = __shfl(cl, l0);
            int c1 = __shfl(cl, l0 + 1);
            int c2 = __shfl(cl, l0 + 2);
            int c3 = __shfl(cl, l0 + 3);
            float v0 = __shfl(vl, l0);
            float v1 = __shfl(vl, l0 + 1);
            float v2 = __shfl(vl, l0 + 2);
            float v3 = __shfl(vl, l0 + 3);
            uint4 p0 = xin[(size_t)c0 * 16 + sub];
            uint4 p1 = xin[(size_t)c1 * 16 + sub];
            uint4 p2 = xin[(size_t)c2 * 16 + sub];
            uint4 p3 = xin[(size_t)c3 * 16 + sub];
            a0 += v0 * blo(p0.x); a1 += v0 * bhi(p0.x); a2 += v0 * blo(p0.y); a3 += v0 * bhi(p0.y);
            a4 += v0 * blo(p0.z); a5 += v0 * bhi(p0.z); a6 += v0 * blo(p0.w); a7 += v0 * bhi(p0.w);
            a0 += v1 * blo(p1.x); a1 += v1 * bhi(p1.x); a2 += v1 * blo(p1.y); a3 += v1 * bhi(p1.y);
            a4 += v1 * blo(p1.z); a5 += v1 * bhi(p1.z); a6 += v1 * blo(p1.w); a7 += v1 * bhi(p1.w);
            a0 += v2 * blo(p2.x); a1 += v2 * bhi(p2.x); a2 += v2 * blo(p2.y); a3 += v2 * bhi(p2.y);
            a4 += v2 * blo(p2.z); a5 += v2 * bhi(p2.z); a6 += v2 * blo(p2.w); a7 += v2 * bhi(p2.w);
            a0 += v3 * blo(p3.x); a1 += v3 * bhi(p3.x); a2 += v3 * blo(p3.y); a3 += v3 * bhi(p3.y);
            a4 += v3 * blo(p3.z); a5 += v3 * bhi(p3.z); a6 += v3 * blo(p3.w); a7 += v3 * bhi(p3.w);
        }
    }

    float id = 1.0f / deg[row];
    a0 *= id; a1 *= id; a2 *= id; a3 *= id; a4 *= id; a5 *= id; a6 *= id; a7 *= id;

    float ss = a0 * a0 + a1 * a1 + a2 * a2 + a3 * a3 + a4 * a4 + a5 * a5 + a6 * a6 + a7 * a7;
#pragma unroll
    for (int m = 1; m <= 8; m <<= 1) ss += __shfl_xor(ss, m);
    float nrm = fmaxf(sqrtf(ss), 1e-12f);
    float w4 = weight / nrm;

    // combine: acc = s1*x1 + s2*x2 + s3*x3 + w4 * (f32 hop-4 row)
    size_t xi = (size_t)row * 16 + sub;
    float w1 = s1[row], w2 = s2[row], w3 = s3[row];
    uint4 q1 = x1[xi], q2 = x2[xi], q3 = x3[xi];
    float v[8];
    v[0] = w1 * blo(q1.x) + w2 * blo(q2.x) + w3 * blo(q3.x) + w4 * a0;
    v[1] = w1 * bhi(q1.x) + w2 * bhi(q2.x) + w3 * bhi(q3.x) + w4 * a1;
    v[2] = w1 * blo(q1.y) + w2 * blo(q2.y) + w3 * blo(q3.y) + w4 * a2;
    v[3] = w1 * bhi(q1.y) + w2 * bhi(q2.y) + w3 * bhi(q3.y) + w4 * a3;
    v[4] = w1 * blo(q1.z) + w2 * blo(q2.z) + w3 * blo(q3.z) + w4 * a4;
    v[5] = w1 * bhi(q1.z) + w2 * bhi(q2.z) + w3 * bhi(q3.z) + w4 * a5;
    v[6] = w1 * blo(q1.w) + w2 * blo(q2.w) + w3 * blo(q3.w) + w4 * a6;
    v[7] = w1 * bhi(q1.w) + w2 * bhi(q2.w) + w3 * bhi(q3.w) + w4 * a7;

    float4* out4 = (float4*)out;
    out4[(size_t)row * 32 + sub * 2]     = make_float4(v[0], v[1], v[2], v[3]);
    out4[(size_t)row * 32 + sub * 2 + 1] = make_float4(v[4], v[5], v[6], v[7]);

    int t = threadIdx.x;
#pragma unroll
    for (int j = 0; j < 8; ++j) {
        shs[t * 8 + j] = v[j];
        shq[t * 8 + j] = v[j] * v[j];
    }
    __syncthreads();
    if (t < DD) {  // column c = t; fold the 16 rows of this block
        int cs = t >> 3, cj = t & 7;
        float sacc = 0.0f, qacc = 0.0f;
        for (int g = 0; g < 16; ++g) {
            int src = (g * 16 + cs) * 8 + cj;
            sacc += shs[src];
            qacc += shq[src];
        }
        psum[(size_t)blockIdx.x * DD + t] = sacc;
        psumsq[(size_t)blockIdx.x * DD + t] = qacc;
    }
}

// ---------------- fold partials per column, compute mean/invstd ----------------
static __global__ __launch_bounds__(256) void fold_kernel(
    const float* __restrict__ psum, const float* __restrict__ psumsq,
    float* __restrict__ mean, float* __restrict__ invstd) {
    __shared__ double ss[256], qq[256];
    int c = blockIdx.x;   // 0..127
    int t = threadIdx.x;
    double s = 0.0, q = 0.0;
    for (int b = t; b < SPMM_NBLK; b += 256) {
        s += (double)psum[(size_t)b * DD + c];
        q += (double)psumsq[(size_t)b * DD + c];
    }
    ss[t] = s; qq[t] = q;
    __syncthreads();
    for (int off = 128; off > 0; off >>= 1) {
        if (t < off) { ss[t] += ss[t + off]; qq[t] += qq[t + off]; }
        __syncthreads();
    }
    if (t == 0) {
        double m = ss[0] / (double)NN;
        double var = (qq[0] - (double)NN * m * m) / (double)(NN - 1);
        if (var < 0.0) var = 0.0;
        double sd = sqrt(var);
        if (sd == 0.0) sd = 1.0;
        mean[c] = (float)m;
        invstd[c] = (float)(1.0 / sd);
    }
}

// ---------------- standardize in place (float4 vectorized) ----------------
static __global__ __launch_bounds__(256) void normalize_kernel(
    float* __restrict__ out, const float* __restrict__ mean, const float* __restrict__ invstd) {
    int i = blockIdx.x * blockDim.x + threadIdx.x;  // over NN*32 float4s
    int c4 = i & 31;
    float4 m = ((const float4*)mean)[c4];
    float4 is = ((const float4*)invstd)[c4];
    float4* out4 = (float4*)out;
    float4 v = out4[i];
    v.x = (v.x - m.x) * is.x;
    v.y = (v.y - m.y) * is.y;
    v.z = (v.z - m.z) * is.z;
    v.w = (v.w - m.w) * is.w;
    out4[i] = v;
}

extern "C" void kernel_launch(void* const* d_in, const int* in_sizes, int n_in,
                              void* d_out, int out_size, void* d_ws, size_t ws_size,
                              hipStream_t stream) {
    const int* erow = (const int*)d_in[0];
    const int* ecol = (const int*)d_in[1];
    const float* eval_ = (const float*)d_in[2];
    const float* R = (const float*)d_in[3];
    float* out = (float*)d_out;

    // workspace layout
    char* ws = (char*)d_ws;
    size_t off = 0;
    auto alloc = [&](size_t bytes) -> char* {
        char* p = ws + off;
        off += (bytes + 255) & ~(size_t)255;
        return p;
    };
    float* deg          = (float*)alloc(NN * sizeof(float));
    int* bucket_cursor  = (int*)alloc((NBKT + 1) * sizeof(int));  // [NBKT] = structure flag
    int* row_start      = (int*)alloc((NN + 1) * sizeof(int));
    uint2* binned       = (uint2*)alloc((size_t)NBKT * BCAP * sizeof(uint2));
    uint2* csr          = (uint2*)alloc((size_t)NE * sizeof(uint2));
    uint4* x0           = (uint4*)alloc((size_t)NN * 16 * sizeof(uint4));  // bf16 packed
    uint4* x1           = (uint4*)alloc((size_t)NN * 16 * sizeof(uint4));
    uint4* x2           = (uint4*)alloc((size_t)NN * 16 * sizeof(uint4));
    uint4* x3           = (uint4*)alloc((size_t)NN * 16 * sizeof(uint4));
    unsigned int* pks   = (unsigned int*)alloc((size_t)NN * 16 * sizeof(unsigned int)); // 64B/row
    float* s1           = (float*)alloc(NN * sizeof(float));
    float* s2           = (float*)alloc(NN * sizeof(float));
    float* s3           = (float*)alloc(NN * sizeof(float));
    float* psum         = (float*)alloc((size_t)SPMM_NBLK * DD * sizeof(float));
    float* psumsq       = (float*)alloc((size_t)SPMM_NBLK * DD * sizeof(float));
    float* meanbuf      = (float*)alloc(DD * sizeof(float));
    float* invstdb      = (float*)alloc(DD * sizeof(float));
    int* sflag          = &bucket_cursor[NBKT];

    hipMemsetAsync(bucket_cursor, 0, (NBKT + 1) * sizeof(int), stream);

    bin_kernel<<<NCHUNK, 512, 0, stream>>>(erow, ecol, eval_, bucket_cursor, binned);
    sort_kernel<<<NBKT, 512, 0, stream>>>(binned, bucket_cursor, csr, row_start, deg);
    pk_kernel<<<SPMM_NBLK, 256, 0, stream>>>(R, deg, x0, pks, sflag);

    spmm_first_kernel<<<SPMM_NBLK, 256, 0, stream>>>(row_start, csr, pks, x0, deg, sflag,
                                                     x1, s1, 1.0f);
    spmm_fused_kernel<<<SPMM_NBLK, 256, 0, stream>>>(row_start, csr, x1, deg, x2, s2, 1.0f);
    spmm_fused_kernel<<<SPMM_NBLK, 256, 0, stream>>>(row_start, csr, x2, deg, x3, s3, 7.81f);
    spmm_last_kernel<<<SPMM_NBLK, 256, 0, stream>>>(row_start, csr, x3, deg, x1, x2, x3,
                                                    s1, s2, s3, out, psum, psumsq, 45.28f);

    fold_kernel<<<DD, 256, 0, stream>>>(psum, psumsq, meanbuf, invstdb);
    normalize_kernel<<<NN * 32 / 256, 256, 0, stream>>>(out, meanbuf, invstdb);
}

// Round 5
// 247.025 us; speedup vs baseline: 1.0294x; 1.0294x over previous
//
#include <hip/hip_runtime.h>
#include <math.h>

#define NN 50000
#define NE 800000
#define DD 128
#define NBKT 256            // buckets; bucket = row / RPB (one block per CU)
#define RPB 196             // rows per bucket (256*196 = 50176 >= NN)
#define BCAP 3840           // per-bucket capacity (mean 3136, sigma 56 -> ~12.5 sigma)
#define CHUNK 4096          // edges per bin_kernel block
#define NCHUNK ((NE + CHUNK - 1) / CHUNK)   // 196
#define SPMM_NBLK (NN / 16) // 3125

// ---------------- bf16 helpers (x stored as bf16 pairs packed in uint) ----------------
static __device__ __forceinline__ float blo(unsigned int p) { return __uint_as_float(p << 16); }
static __device__ __forceinline__ float bhi(unsigned int p) { return __uint_as_float(p & 0xffff0000u); }
static __device__ __forceinline__ unsigned int pack2bf(float a, float b) {
    unsigned int ua = __float_as_uint(a);
    unsigned int ub = __float_as_uint(b);
    ua = ua + 0x7FFFu + ((ua >> 16) & 1u);
    ub = ub + 0x7FFFu + ((ub >> 16) & 1u);
    return (ua >> 16) | (ub & 0xffff0000u);
}

// ---------------- pass 1: LDS counting-sort edges into 256 coarse buckets ----------------
// payload: uint2{ row | col<<16, val_bits }  (row, col < 65536)
static __global__ __launch_bounds__(512) void bin_kernel(
    const int* __restrict__ erow, const int* __restrict__ ecol, const float* __restrict__ eval_,
    int* __restrict__ bucket_cursor, uint2* __restrict__ binned) {
    __shared__ uint2 sorted[CHUNK];       // 32 KB
    __shared__ unsigned char sbin[CHUNK]; // 4 KB
    __shared__ int hist[NBKT];
    __shared__ int bstart[NBKT];
    __shared__ int bcur[NBKT];
    __shared__ int gbase[NBKT];
    __shared__ int tmp[NBKT];

    int t = threadIdx.x;
    int cbase = blockIdx.x * CHUNK;
    int cn = NE - cbase; if (cn > CHUNK) cn = CHUNK;

    for (int i = t; i < NBKT; i += 512) hist[i] = 0;
    __syncthreads();

    unsigned int rc[8]; unsigned int vv[8]; int bb[8];
    int nloc = 0;
    for (int i = t; i < cn; i += 512) {
        int g = cbase + i;
        int r = erow[g];
        int c = ecol[g];
        float v = eval_[g];
        rc[nloc] = (unsigned)r | ((unsigned)c << 16);
        vv[nloc] = __float_as_uint(v);
        int b = r / RPB;            // compiler emits magic-multiply
        bb[nloc] = b;
        atomicAdd(&hist[b], 1);
        ++nloc;
    }
    __syncthreads();

    // exclusive scan of hist over 256 entries (first 256 threads; all hit barriers)
    int hv = (t < NBKT) ? hist[t] : 0;
    if (t < NBKT) tmp[t] = hv;
    __syncthreads();
    for (int off = 1; off < NBKT; off <<= 1) {
        int u = (t < NBKT && t >= off) ? tmp[t - off] : 0;
        __syncthreads();
        if (t < NBKT) tmp[t] += u;
        __syncthreads();
    }
    if (t < NBKT) {
        int ex = tmp[t] - hv;
        bstart[t] = ex;
        bcur[t] = ex;
        gbase[t] = atomicAdd(&bucket_cursor[t], hv);  // reserve contiguous run in bucket region
    }
    __syncthreads();

    // scatter into LDS (sorted by bucket)
    for (int k = 0; k < nloc; ++k) {
        int pos = atomicAdd(&bcur[bb[k]], 1);
        sorted[pos] = make_uint2(rc[k], vv[k]);
        sbin[pos] = (unsigned char)bb[k];
    }
    __syncthreads();

    // coalesced write-out: consecutive i in same bucket -> consecutive global slots
    for (int i = t; i < cn; i += 512) {
        int b = sbin[i];
        binned[(size_t)b * BCAP + gbase[b] + (i - bstart[b])] = sorted[i];
    }
}

// ---------------- pass 2: per-bucket sort by row -> CSR + row_start + deg ----------
static __global__ __launch_bounds__(512) void sort_kernel(
    const uint2* __restrict__ binned, const int* __restrict__ bucket_cursor,
    uint2* __restrict__ csr, int* __restrict__ row_start, float* __restrict__ deg) {
    __shared__ uint2 buf[BCAP];       // 30 KB
    __shared__ int hist[RPB];
    __shared__ int rcur[RPB];
    __shared__ float fdeg[RPB];
    __shared__ int pscan[NBKT];
    int b = blockIdx.x;
    int t = threadIdx.x;
    int lo = b * RPB;

    // inclusive scan over all bucket counts -> per-block base + count
    int pv = (t < NBKT) ? bucket_cursor[t] : 0;
    if (t < NBKT) pscan[t] = pv;
    if (t < RPB) { hist[t] = 0; fdeg[t] = 0.0f; }
    __syncthreads();
    for (int off = 1; off < NBKT; off <<= 1) {
        int u = (t < NBKT && t >= off) ? pscan[t - off] : 0;
        __syncthreads();
        if (t < NBKT) pscan[t] += u;
        __syncthreads();
    }
    int gb = (b == 0) ? 0 : pscan[b - 1];
    int cnt = pscan[b] - gb;

    for (int i = t; i < cnt; i += 512) {
        uint2 e = binned[(size_t)b * BCAP + i];
        buf[i] = e;
        int rr = (int)(e.x & 0xFFFFu) - lo;
        atomicAdd(&hist[rr], 1);
        atomicAdd(&fdeg[rr], __uint_as_float(e.y));
    }
    __syncthreads();
    // inclusive scan of per-row counts (196 entries)
    int hv = (t < RPB) ? hist[t] : 0;
    if (t < RPB) rcur[t] = hv;
    __syncthreads();
    for (int off = 1; off < RPB; off <<= 1) {
        int u = (t < RPB && t >= off) ? rcur[t - off] : 0;
        __syncthreads();
        if (t < RPB) rcur[t] += u;
        __syncthreads();
    }
    if (t < RPB) {
        int excl = rcur[t] - hv;
        int r = lo + t;
        if (r < NN) {
            row_start[r] = gb + excl;
            float d = fdeg[t];
            deg[r] = (d == 0.0f) ? 1.0f : d;
        }
        rcur[t] = excl;
    }
    if (b == NBKT - 1 && t == 0) row_start[NN] = gb + cnt;
    __syncthreads();
    for (int i = t; i < cnt; i += 512) {
        uint2 e = buf[i];
        int rr = (int)(e.x & 0xFFFFu) - lo;
        int pos = atomicAdd(&rcur[rr], 1);
        csr[(size_t)gb + pos] = make_uint2(e.x >> 16, e.y);
    }
}

// ---------------- x0 = R * deg^(-1/2), bf16-packed (fully parallel) ----------------
static __global__ __launch_bounds__(256) void x0_kernel(
    const float* __restrict__ R, const float* __restrict__ deg, uint4* __restrict__ x0) {
    int idx = blockIdx.x * 256 + threadIdx.x;   // over NN*16 uint4s (= 800000, exact grid)
    int row = idx >> 4;
    float sc = rsqrtf(deg[row]);                // deg already has 0 -> 1 fix
    const float4* __restrict__ R4 = (const float4*)R;
    float4 f0 = R4[(size_t)idx * 2];
    float4 f1 = R4[(size_t)idx * 2 + 1];
    x0[idx] = make_uint4(pack2bf(f0.x * sc, f0.y * sc), pack2bf(f0.z * sc, f0.w * sc),
                         pack2bf(f1.x * sc, f1.y * sc), pack2bf(f1.z * sc, f1.w * sc));
}

// ---------------- fused SpMM + inv_deg + row-norm scalar (hops 1-3) ----------------
// 256 threads = 4 waves; each wave handles 4 rows, one per 16-lane quarter.
static __global__ __launch_bounds__(256) void spmm_fused_kernel(
    const int* __restrict__ row_start, const uint2* __restrict__ csr,
    const uint4* __restrict__ x4, const float* __restrict__ deg,
    uint4* __restrict__ x_next4, float* __restrict__ s_out, float weight) {
    int wave = threadIdx.x >> 6;
    int lane = threadIdx.x & 63;
    int quarter = lane >> 4;  // 0..3 : which row of the wave's 4
    int sub = lane & 15;      // col group: cols [8*sub, 8*sub+7]
    int row = blockIdx.x * 16 + wave * 4 + quarter;
    int s = row_start[row];
    int e = row_start[row + 1];

    float a0 = 0.f, a1 = 0.f, a2 = 0.f, a3 = 0.f, a4 = 0.f, a5 = 0.f, a6 = 0.f, a7 = 0.f;
    for (int base = s; base < e; base += 16) {
        int j = base + sub;
        int cl = 0;
        float vl = 0.0f;
        if (j < e) { uint2 t2 = csr[j]; cl = (int)t2.x; vl = __uint_as_float(t2.y); }
        int cnt = e - base; if (cnt > 16) cnt = 16;
        for (int k = 0; k < cnt; k += 4) {
            int l0 = quarter * 16 + k;
            int c0 = __shfl(cl, l0);
            int c1 = __shfl(cl, l0 + 1);
            int c2 = __shfl(cl, l0 + 2);
            int c3 = __shfl(cl, l0 + 3);
            float v0 = __shfl(vl, l0);
            float v1 = __shfl(vl, l0 + 1);
            float v2 = __shfl(vl, l0 + 2);
            float v3 = __shfl(vl, l0 + 3);  // entries past cnt have vl=0 -> contribute 0
            uint4 p0 = x4[(size_t)c0 * 16 + sub];
            uint4 p1 = x4[(size_t)c1 * 16 + sub];
            uint4 p2 = x4[(size_t)c2 * 16 + sub];
            uint4 p3 = x4[(size_t)c3 * 16 + sub];
            a0 += v0 * blo(p0.x); a1 += v0 * bhi(p0.x); a2 += v0 * blo(p0.y); a3 += v0 * bhi(p0.y);
            a4 += v0 * blo(p0.z); a5 += v0 * bhi(p0.z); a6 += v0 * blo(p0.w); a7 += v0 * bhi(p0.w);
            a0 += v1 * blo(p1.x); a1 += v1 * bhi(p1.x); a2 += v1 * blo(p1.y); a3 += v1 * bhi(p1.y);
            a4 += v1 * blo(p1.z); a5 += v1 * bhi(p1.z); a6 += v1 * blo(p1.w); a7 += v1 * bhi(p1.w);
            a0 += v2 * blo(p2.x); a1 += v2 * bhi(p2.x); a2 += v2 * blo(p2.y); a3 += v2 * bhi(p2.y);
            a4 += v2 * blo(p2.z); a5 += v2 * bhi(p2.z); a6 += v2 * blo(p2.w); a7 += v2 * bhi(p2.w);
            a0 += v3 * blo(p3.x); a1 += v3 * bhi(p3.x); a2 += v3 * blo(p3.y); a3 += v3 * bhi(p3.y);
            a4 += v3 * blo(p3.z); a5 += v3 * bhi(p3.z); a6 += v3 * blo(p3.w); a7 += v3 * bhi(p3.w);
        }
    }

    float id = 1.0f / deg[row];
    a0 *= id; a1 *= id; a2 *= id; a3 *= id; a4 *= id; a5 *= id; a6 *= id; a7 *= id;

    float ss = a0 * a0 + a1 * a1 + a2 * a2 + a3 * a3 + a4 * a4 + a5 * a5 + a6 * a6 + a7 * a7;
#pragma unroll
    for (int m = 1; m <= 8; m <<= 1) ss += __shfl_xor(ss, m);
    float nrm = fmaxf(sqrtf(ss), 1e-12f);

    x_next4[(size_t)row * 16 + sub] = make_uint4(pack2bf(a0, a1), pack2bf(a2, a3),
                                                 pack2bf(a4, a5), pack2bf(a6, a7));
    if (sub == 0) s_out[row] = weight / nrm;
}

// ---------------- hop 4: SpMM + combine acc(out) + per-block column stats ----------------
static __global__ __launch_bounds__(256) void spmm_last_kernel(
    const int* __restrict__ row_start, const uint2* __restrict__ csr,
    const uint4* __restrict__ xin, const float* __restrict__ deg,
    const uint4* __restrict__ x1, const uint4* __restrict__ x2, const uint4* __restrict__ x3,
    const float* __restrict__ s1, const float* __restrict__ s2, const float* __restrict__ s3,
    float* __restrict__ out, float* __restrict__ psum, float* __restrict__ psumsq, float weight) {
    __shared__ float shs[256 * 8];
    __shared__ float shq[256 * 8];
    int wave = threadIdx.x >> 6;
    int lane = threadIdx.x & 63;
    int quarter = lane >> 4;
    int sub = lane & 15;
    int row = blockIdx.x * 16 + wave * 4 + quarter;
    int s = row_start[row];
    int e = row_start[row + 1];

    float a0 = 0.f, a1 = 0.f, a2 = 0.f, a3 = 0.f, a4 = 0.f, a5 = 0.f, a6 = 0.f, a7 = 0.f;
    for (int base = s; base < e; base += 16) {
        int j = base + sub;
        int cl = 0;
        float vl = 0.0f;
        if (j < e) { uint2 t2 = csr[j]; cl = (int)t2.x; vl = __uint_as_float(t2.y); }
        int cnt = e - base; if (cnt > 16) cnt = 16;
        for (int k = 0; k < cnt; k += 4) {
            int l0 = quarter * 16 + k;
            int c0 = __shfl(cl, l0);
            int c1 = __shfl(cl, l0 + 1);
            int c2 = __shfl(cl, l0 + 2);
            int c3 = __shfl(cl, l0 + 3);
            float v0 = __shfl(vl, l0);
            float v1 = __shfl(vl, l0 + 1);
            float v2 = __shfl(vl, l0 + 2);
            float v3 = __shfl(vl, l0 + 3);
            uint4 p0 = xin[(size_t)c0 * 16 + sub];
            uint4 p1 = xin[(size_t)c1 * 16 + sub];
            uint4 p2 = xin[(size_t)c2 * 16 + sub];
            uint4 p3 = xin[(size_t)c3 * 16 + sub];
            a0 += v0 * blo(p0.x); a1 += v0 * bhi(p0.x); a2 += v0 * blo(p0.y); a3 += v0 * bhi(p0.y);
            a4 += v0 * blo(p0.z); a5 += v0 * bhi(p0.z); a6 += v0 * blo(p0.w); a7 += v0 * bhi(p0.w);
            a0 += v1 * blo(p1.x); a1 += v1 * bhi(p1.x); a2 += v1 * blo(p1.y); a3 += v1 * bhi(p1.y);
            a4 += v1 * blo(p1.z); a5 += v1 * bhi(p1.z); a6 += v1 * blo(p1.w); a7 += v1 * bhi(p1.w);
            a0 += v2 * blo(p2.x); a1 += v2 * bhi(p2.x); a2 += v2 * blo(p2.y); a3 += v2 * bhi(p2.y);
            a4 += v2 * blo(p2.z); a5 += v2 * bhi(p2.z); a6 += v2 * blo(p2.w); a7 += v2 * bhi(p2.w);
            a0 += v3 * blo(p3.x); a1 += v3 * bhi(p3.x); a2 += v3 * blo(p3.y); a3 += v3 * bhi(p3.y);
            a4 += v3 * blo(p3.z); a5 += v3 * bhi(p3.z); a6 += v3 * blo(p3.w); a7 += v3 * bhi(p3.w);
        }
    }

    float id = 1.0f / deg[row];
    a0 *= id; a1 *= id; a2 *= id; a3 *= id; a4 *= id; a5 *= id; a6 *= id; a7 *= id;

    float ss = a0 * a0 + a1 * a1 + a2 * a2 + a3 * a3 + a4 * a4 + a5 * a5 + a6 * a6 + a7 * a7;
#pragma unroll
    for (int m = 1; m <= 8; m <<= 1) ss += __shfl_xor(ss, m);
    float nrm = fmaxf(sqrtf(ss), 1e-12f);
    float w4 = weight / nrm;

    // combine: acc = s1*x1 + s2*x2 + s3*x3 + w4 * (f32 hop-4 row)
    size_t xi = (size_t)row * 16 + sub;
    float w1 = s1[row], w2 = s2[row], w3 = s3[row];
    uint4 q1 = x1[xi], q2 = x2[xi], q3 = x3[xi];
    float v[8];
    v[0] = w1 * blo(q1.x) + w2 * blo(q2.x) + w3 * blo(q3.x) + w4 * a0;
    v[1] = w1 * bhi(q1.x) + w2 * bhi(q2.x) + w3 * bhi(q3.x) + w4 * a1;
    v[2] = w1 * blo(q1.y) + w2 * blo(q2.y) + w3 * blo(q3.y) + w4 * a2;
    v[3] = w1 * bhi(q1.y) + w2 * bhi(q2.y) + w3 * bhi(q3.y) + w4 * a3;
    v[4] = w1 * blo(q1.z) + w2 * blo(q2.z) + w3 * blo(q3.z) + w4 * a4;
    v[5] = w1 * bhi(q1.z) + w2 * bhi(q2.z) + w3 * bhi(q3.z) + w4 * a5;
    v[6] = w1 * blo(q1.w) + w2 * blo(q2.w) + w3 * blo(q3.w) + w4 * a6;
    v[7] = w1 * bhi(q1.w) + w2 * bhi(q2.w) + w3 * bhi(q3.w) + w4 * a7;

    float4* out4 = (float4*)out;
    out4[(size_t)row * 32 + sub * 2]     = make_float4(v[0], v[1], v[2], v[3]);
    out4[(size_t)row * 32 + sub * 2 + 1] = make_float4(v[4], v[5], v[6], v[7]);

    int t = threadIdx.x;
#pragma unroll
    for (int j = 0; j < 8; ++j) {
        shs[t * 8 + j] = v[j];
        shq[t * 8 + j] = v[j] * v[j];
    }
    __syncthreads();
    if (t < DD) {  // column c = t; fold the 16 rows of this block
        int cs = t >> 3, cj = t & 7;
        float sacc = 0.0f, qacc = 0.0f;
        for (int g = 0; g < 16; ++g) {
            int src = (g * 16 + cs) * 8 + cj;
            sacc += shs[src];
            qacc += shq[src];
        }
        psum[(size_t)blockIdx.x * DD + t] = sacc;
        psumsq[(size_t)blockIdx.x * DD + t] = qacc;
    }
}

// ---------------- fold partials per column, compute mean/invstd ----------------
static __global__ __launch_bounds__(256) void fold_kernel(
    const float* __restrict__ psum, const float* __restrict__ psumsq,
    float* __restrict__ mean, float* __restrict__ invstd) {
    __shared__ double ss[256], qq[256];
    int c = blockIdx.x;   // 0..127
    int t = threadIdx.x;
    double s = 0.0, q = 0.0;
    for (int b = t; b < SPMM_NBLK; b += 256) {
        s += (double)psum[(size_t)b * DD + c];
        q += (double)psumsq[(size_t)b * DD + c];
    }
    ss[t] = s; qq[t] = q;
    __syncthreads();
    for (int off = 128; off > 0; off >>= 1) {
        if (t < off) { ss[t] += ss[t + off]; qq[t] += qq[t + off]; }
        __syncthreads();
    }
    if (t == 0) {
        double m = ss[0] / (double)NN;
        double var = (qq[0] - (double)NN * m * m) / (double)(NN - 1);
        if (var < 0.0) var = 0.0;
        double sd = sqrt(var);
        if (sd == 0.0) sd = 1.0;
        mean[c] = (float)m;
        invstd[c] = (float)(1.0 / sd);
    }
}

// ---------------- standardize in place (float4 vectorized) ----------------
static __global__ __launch_bounds__(256) void normalize_kernel(
    float* __restrict__ out, const float* __restrict__ mean, const float* __restrict__ invstd) {
    int i = blockIdx.x * blockDim.x + threadIdx.x;  // over NN*32 float4s
    int c4 = i & 31;
    float4 m = ((const float4*)mean)[c4];
    float4 is = ((const float4*)invstd)[c4];
    float4* out4 = (float4*)out;
    float4 v = out4[i];
    v.x = (v.x - m.x) * is.x;
    v.y = (v.y - m.y) * is.y;
    v.z = (v.z - m.z) * is.z;
    v.w = (v.w - m.w) * is.w;
    out4[i] = v;
}

extern "C" void kernel_launch(void* const* d_in, const int* in_sizes, int n_in,
                              void* d_out, int out_size, void* d_ws, size_t ws_size,
                              hipStream_t stream) {
    const int* erow = (const int*)d_in[0];
    const int* ecol = (const int*)d_in[1];
    const float* eval_ = (const float*)d_in[2];
    const float* R = (const float*)d_in[3];
    float* out = (float*)d_out;

    // workspace layout
    char* ws = (char*)d_ws;
    size_t off = 0;
    auto alloc = [&](size_t bytes) -> char* {
        char* p = ws + off;
        off += (bytes + 255) & ~(size_t)255;
        return p;
    };
    float* deg          = (float*)alloc(NN * sizeof(float));
    int* bucket_cursor  = (int*)alloc(NBKT * sizeof(int));
    int* row_start      = (int*)alloc((NN + 1) * sizeof(int));
    uint2* binned       = (uint2*)alloc((size_t)NBKT * BCAP * sizeof(uint2));
    uint2* csr          = (uint2*)alloc((size_t)NE * sizeof(uint2));
    uint4* x0           = (uint4*)alloc((size_t)NN * 16 * sizeof(uint4));  // bf16 packed
    uint4* x1           = (uint4*)alloc((size_t)NN * 16 * sizeof(uint4));
    uint4* x2           = (uint4*)alloc((size_t)NN * 16 * sizeof(uint4));
    uint4* x3           = (uint4*)alloc((size_t)NN * 16 * sizeof(uint4));
    float* s1           = (float*)alloc(NN * sizeof(float));
    float* s2           = (float*)alloc(NN * sizeof(float));
    float* s3           = (float*)alloc(NN * sizeof(float));
    float* psum         = (float*)alloc((size_t)SPMM_NBLK * DD * sizeof(float));
    float* psumsq       = (float*)alloc((size_t)SPMM_NBLK * DD * sizeof(float));
    float* meanbuf      = (float*)alloc(DD * sizeof(float));
    float* invstdb      = (float*)alloc(DD * sizeof(float));

    hipMemsetAsync(bucket_cursor, 0, NBKT * sizeof(int), stream);

    bin_kernel<<<NCHUNK, 512, 0, stream>>>(erow, ecol, eval_, bucket_cursor, binned);
    sort_kernel<<<NBKT, 512, 0, stream>>>(binned, bucket_cursor, csr, row_start, deg);
    x0_kernel<<<SPMM_NBLK, 256, 0, stream>>>(R, deg, x0);

    spmm_fused_kernel<<<SPMM_NBLK, 256, 0, stream>>>(row_start, csr, x0, deg, x1, s1, 1.0f);
    spmm_fused_kernel<<<SPMM_NBLK, 256, 0, stream>>>(row_start, csr, x1, deg, x2, s2, 1.0f);
    spmm_fused_kernel<<<SPMM_NBLK, 256, 0, stream>>>(row_start, csr, x2, deg, x3, s3, 7.81f);
    spmm_last_kernel<<<SPMM_NBLK, 256, 0, stream>>>(row_start, csr, x3, deg, x1, x2, x3,
                                                    s1, s2, s3, out, psum, psumsq, 45.28f);

    fold_kernel<<<DD, 256, 0, stream>>>(psum, psumsq, meanbuf, invstdb);
    normalize_kernel<<<NN * 32 / 256, 256, 0, stream>>>(out, meanbuf, invstdb);
}